// Round 7
// baseline (515.800 us; speedup 1.0000x reference)
//
#include <hip/hip_runtime.h>

#define N_NODES 50000
#define N_EDGES 800000
#define D1 64
#define D2 32
#define N_CLASSES 6
#define N_GRAPHS 128
#define CAP 64      // per-node src bucket capacity; deg ~ Binom(800k,1/50k) mean 16
#define NSLICE 16
#define SLICEN (N_NODES / NSLICE)   // 3125
#define ECHUNK (N_EDGES / 32)       // 25000

typedef unsigned short u16;
typedef __attribute__((ext_vector_type(8))) short bf16x8;
typedef __attribute__((ext_vector_type(4))) float f32x4;

__device__ __forceinline__ float bf2f(u16 b) {
    unsigned int u = ((unsigned int)b) << 16;
    float f;
    __builtin_memcpy(&f, &u, 4);
    return f;
}
__device__ __forceinline__ u16 f2bf(float f) {
    unsigned int u;
    __builtin_memcpy(&u, &f, 4);
    unsigned int r = (u + 0x7fffu + ((u >> 16) & 1u)) >> 16;
    return (u16)r;
}
__device__ __forceinline__ void split8(const float* v, bf16x8& hi, bf16x8& lo) {
#pragma unroll
    for (int j = 0; j < 8; ++j) {
        u16 h = f2bf(v[j]);
        hi[j] = (short)h;
        lo[j] = (short)f2bf(v[j] - bf2f(h));
    }
}
__device__ __forceinline__ float sigmoidf_(float x) {
    return 1.0f / (1.0f + __expf(-x));
}
__device__ __forceinline__ float tanhf_(float x) {
    return 1.0f - 2.0f / (__expf(2.0f * x) + 1.0f);
}

// ============ XCD-sliced bucketed fill (deg pre-zeroed via memset) ============
// slice = blockIdx & 15 -> (presumed) fixed XCD via round-robin dispatch; each
// slice's 400 KB srcidx region is written by one XCD only -> L2 write merging.
__global__ __launch_bounds__(256) void fill_kernel(const int* __restrict__ ei,
                                                   int* __restrict__ deg,
                                                   u16* __restrict__ srcidx) {
    int slice = blockIdx.x & 15;
    int chunk = blockIdx.x >> 4;  // 0..31
    int lo = slice * SLICEN, hi = lo + SLICEN;
    const int* dstp = ei + N_EDGES + chunk * ECHUNK;
    const int* srcp = ei + chunk * ECHUNK;
    for (int i = threadIdx.x; i < ECHUNK; i += 256) {
        int d = dstp[i];
        if (d >= lo && d < hi) {
            int p = atomicAdd(&deg[d], 1);
            if (p < CAP) srcidx[d * CAP + p] = (u16)srcp[i];
        }
    }
}

// ================= fused weight packing =================
__global__ __launch_bounds__(256) void pack_all_kernel(const float* __restrict__ wih,
                                                       const float* __restrict__ whh,
                                                       const float* __restrict__ W,
                                                       const float* __restrict__ bih,
                                                       const float* __restrict__ bhh,
                                                       short* __restrict__ Bh,
                                                       short* __restrict__ Bl,
                                                       short* __restrict__ Wh,
                                                       short* __restrict__ Wl,
                                                       float* __restrict__ bias4) {
    int b = blockIdx.x;
    if (b < 128) {
        int idx = b * 256 + threadIdx.x;
        int j = idx & 7;
        int lane = (idx >> 3) & 63;
        int nt = (idx >> 9) & 15;
        int kt = idx >> 13;
        int k = kt * 32 + (lane >> 4) * 8 + j;
        int n = nt * 16 + (lane & 15);
        int g = n >> 6, d = n & 63;
        float v;
        if (g == 0)      v = (k < 64) ? wih[d * 64 + k] : whh[d * 64 + (k - 64)];
        else if (g == 1) v = (k < 64) ? wih[(64 + d) * 64 + k] : whh[(64 + d) * 64 + (k - 64)];
        else if (g == 2) v = (k < 64) ? wih[(128 + d) * 64 + k] : 0.f;
        else             v = (k < 64) ? 0.f : whh[(128 + d) * 64 + (k - 64)];
        u16 hi = f2bf(v);
        Bh[idx] = (short)hi;
        Bl[idx] = (short)f2bf(v - bf2f(hi));
    } else if (b < 160) {
        int idx = (b - 128) * 256 + threadIdx.x;
        int j = idx & 7;
        int lane = (idx >> 3) & 63;
        int nt = (idx >> 9) & 3;
        int kt = (idx >> 11) & 1;
        int L = idx >> 12;
        int k = kt * 32 + (lane >> 4) * 8 + j;
        int n = nt * 16 + (lane & 15);
        float v = W[L * 4096 + k * 64 + n];
        u16 hi = f2bf(v);
        Wh[idx] = (short)hi;
        Wl[idx] = (short)f2bf(v - bf2f(hi));
    } else {
        int j = threadIdx.x;
        if (j < 64) {
            bias4[j] = bih[j] + bhh[j];
            bias4[64 + j] = bih[64 + j] + bhh[64 + j];
            bias4[128 + j] = bih[128 + j];
            bias4[192 + j] = bhh[128 + j];
        }
    }
}

// ================= MFMA GEMMs =================
// m = hin @ W_L. L0: A from x (f32, split in-register); else from hhi/hlo.
template <bool L0>
__global__ __launch_bounds__(256) void mm_mfma(const float* __restrict__ xf,
                                               const short* __restrict__ Ahi,
                                               const short* __restrict__ Alo,
                                               const short* __restrict__ Wh,
                                               const short* __restrict__ Wl,
                                               float* __restrict__ m) {
    int lane = threadIdx.x & 63;
    int wv = threadIdx.x >> 6;
    int node0 = blockIdx.x * 64 + wv * 16;
    if (node0 >= N_NODES) return;
    int c0 = lane & 15, qr = lane >> 4;

    f32x4 acc[4];
#pragma unroll
    for (int nt = 0; nt < 4; ++nt) acc[nt] = (f32x4){0.f, 0.f, 0.f, 0.f};

#pragma unroll
    for (int kt = 0; kt < 2; ++kt) {
        int aoff = (node0 + c0) * 64 + kt * 32 + qr * 8;
        bf16x8 ah, al;
        if (L0) {
            float tmp[8];
#pragma unroll
            for (int j = 0; j < 8; ++j) tmp[j] = xf[aoff + j];
            split8(tmp, ah, al);
        } else {
            ah = *(const bf16x8*)(Ahi + aoff);
            al = *(const bf16x8*)(Alo + aoff);
        }
#pragma unroll
        for (int nt = 0; nt < 4; ++nt) {
            int boff = (kt * 4 + nt) * 512 + lane * 8;
            bf16x8 bh = *(const bf16x8*)(Wh + boff);
            bf16x8 bl = *(const bf16x8*)(Wl + boff);
            acc[nt] = __builtin_amdgcn_mfma_f32_16x16x32_bf16(ah, bh, acc[nt], 0, 0, 0);
            acc[nt] = __builtin_amdgcn_mfma_f32_16x16x32_bf16(ah, bl, acc[nt], 0, 0, 0);
            acc[nt] = __builtin_amdgcn_mfma_f32_16x16x32_bf16(al, bh, acc[nt], 0, 0, 0);
        }
    }
#pragma unroll
    for (int nt = 0; nt < 4; ++nt)
#pragma unroll
        for (int r = 0; r < 4; ++r)
            m[(node0 + qr * 4 + r) * 64 + nt * 16 + c0] = acc[nt][r];
}

// ======= fused aggregate + GRU: gather agg rows -> wave-local LDS -> A-frags,
// then GEMM vs packed B, then gate epilogue (+ bf16 split of h_out). =======
template <bool L0>
__global__ __launch_bounds__(256) void gruagg_mfma(const float* __restrict__ m,
                                                   const int* __restrict__ deg,
                                                   const u16* __restrict__ srcidx,
                                                   const float* __restrict__ hin,  // x (L0) or h f32
                                                   short* hhi, short* hlo,
                                                   const short* __restrict__ Bh,
                                                   const short* __restrict__ Bl,
                                                   const float* __restrict__ bias4,
                                                   float* __restrict__ hout) {
    __shared__ float at[4][16][65];  // +65 pad: 2-way bank aliasing only (free)
    int lane = threadIdx.x & 63;
    int wv = threadIdx.x >> 6;
    int node0 = blockIdx.x * 64 + wv * 16;
    if (node0 >= N_NODES) return;  // wave-granular; no barriers in this kernel
    int c0 = lane & 15, qr = lane >> 4;
    float(*myat)[65] = at[wv];

    // --- gather: agg rows for this wave's 16 nodes, lane = feature ---
    for (int r = 0; r < 16; ++r) {
        int node = node0 + r;
        int cnt = __builtin_amdgcn_readfirstlane(deg[node]);
        cnt = cnt < CAP ? cnt : CAP;
        const u16* bucket = srcidx + node * CAP;
        float acc = 0.f;
        int k = 0;
        for (; k + 4 <= cnt; k += 4) {
            int s0 = __builtin_amdgcn_readfirstlane((int)bucket[k]);
            int s1 = __builtin_amdgcn_readfirstlane((int)bucket[k + 1]);
            int s2 = __builtin_amdgcn_readfirstlane((int)bucket[k + 2]);
            int s3 = __builtin_amdgcn_readfirstlane((int)bucket[k + 3]);
            acc += m[s0 * 64 + lane];
            acc += m[s1 * 64 + lane];
            acc += m[s2 * 64 + lane];
            acc += m[s3 * 64 + lane];
        }
        for (; k < cnt; ++k) {
            int s = __builtin_amdgcn_readfirstlane((int)bucket[k]);
            acc += m[s * 64 + lane];
        }
        myat[r][lane] = acc;
    }
    // wave-local LDS: no __syncthreads needed (compiler inserts lgkmcnt waits)

    f32x4 acc[16];
#pragma unroll
    for (int nt = 0; nt < 16; ++nt) acc[nt] = (f32x4){0.f, 0.f, 0.f, 0.f};

#pragma unroll
    for (int kt = 0; kt < 4; ++kt) {
        bf16x8 ah, al;
        if (kt < 2) {  // agg half: A-frag from LDS tile (transpose read)
            float tmp[8];
#pragma unroll
            for (int j = 0; j < 8; ++j) tmp[j] = myat[c0][kt * 32 + qr * 8 + j];
            split8(tmp, ah, al);
        } else {  // h half
            int aoff = (node0 + c0) * 64 + (kt & 1) * 32 + qr * 8;
            if (L0) {
                float tmp[8];
#pragma unroll
                for (int j = 0; j < 8; ++j) tmp[j] = hin[aoff + j];
                split8(tmp, ah, al);
            } else {
                ah = *(const bf16x8*)(hhi + aoff);
                al = *(const bf16x8*)(hlo + aoff);
            }
        }
#pragma unroll
        for (int nt = 0; nt < 16; ++nt) {
            int boff = (kt * 16 + nt) * 512 + lane * 8;
            bf16x8 bh = *(const bf16x8*)(Bh + boff);
            bf16x8 bl = *(const bf16x8*)(Bl + boff);
            acc[nt] = __builtin_amdgcn_mfma_f32_16x16x32_bf16(ah, bh, acc[nt], 0, 0, 0);
            acc[nt] = __builtin_amdgcn_mfma_f32_16x16x32_bf16(ah, bl, acc[nt], 0, 0, 0);
            acc[nt] = __builtin_amdgcn_mfma_f32_16x16x32_bf16(al, bh, acc[nt], 0, 0, 0);
        }
    }

    // gates: cols j, 64+j, 128+j, 192+j live in n-tiles jt, jt+4, jt+8, jt+12
#pragma unroll
    for (int r = 0; r < 4; ++r) {
        int row = node0 + qr * 4 + r;
#pragma unroll
        for (int jt = 0; jt < 4; ++jt) {
            int j = jt * 16 + c0;
            float rr = sigmoidf_(acc[jt][r] + bias4[j]);
            float zz = sigmoidf_(acc[4 + jt][r] + bias4[64 + j]);
            float nn = tanhf_(acc[8 + jt][r] + bias4[128 + j] +
                              rr * (acc[12 + jt][r] + bias4[192 + j]));
            float ho = hin[row * 64 + j];
            float v = (1.f - zz) * nn + zz * ho;
            hout[row * 64 + j] = v;
            u16 hi = f2bf(v);
            hhi[row * 64 + j] = (short)hi;
            hlo[row * 64 + j] = (short)f2bf(v - bf2f(hi));
        }
    }
}

// relu + segment-mean pool
__global__ __launch_bounds__(256) void pool_kernel(const float* __restrict__ h,
                                                   const int* __restrict__ batch,
                                                   float* __restrict__ pooled) {
    int g = blockIdx.x;
    int tid = threadIdx.x, lane = tid & 63, wv = tid >> 6;
    int lo, hi;
    {
        int a = 0, b = N_NODES;
        while (a < b) { int mid = (a + b) >> 1; if (batch[mid] < g) a = mid + 1; else b = mid; }
        lo = a;
    }
    {
        int a = lo, b = N_NODES;
        while (a < b) { int mid = (a + b) >> 1; if (batch[mid] < g + 1) a = mid + 1; else b = mid; }
        hi = a;
    }
    float acc = 0.f;
    for (int n = lo + wv; n < hi; n += 4) acc += fmaxf(h[n * 64 + lane], 0.f);
    __shared__ float red[4][64];
    red[wv][lane] = acc;
    __syncthreads();
    if (wv == 0) {
        float s = red[0][lane] + red[1][lane] + red[2][lane] + red[3][lane];
        float cnt = (float)(hi - lo);
        pooled[g * 64 + lane] = s / fmaxf(cnt, 1.f);
    }
}

// head: fc1+relu, fc2, log_softmax
__global__ __launch_bounds__(64) void head_kernel(const float* __restrict__ pooled,
                                                  const float* __restrict__ fc1w,
                                                  const float* __restrict__ fc1b,
                                                  const float* __restrict__ fc2w,
                                                  const float* __restrict__ fc2b,
                                                  float* __restrict__ out) {
    int g = blockIdx.x;
    int lane = threadIdx.x;
    __shared__ float pv[64];
    __shared__ float s1[32];
    __shared__ float s2[6];
    pv[lane] = pooled[g * 64 + lane];
    __syncthreads();
    if (lane < 32) {
        float acc = fc1b[lane];
#pragma unroll
        for (int j = 0; j < 64; ++j) acc = fmaf(pv[j], fc1w[lane * 64 + j], acc);
        s1[lane] = fmaxf(acc, 0.f);
    }
    __syncthreads();
    if (lane < 6) {
        float acc = fc2b[lane];
#pragma unroll
        for (int j = 0; j < 32; ++j) acc = fmaf(s1[j], fc2w[lane * 32 + j], acc);
        s2[lane] = acc;
    }
    __syncthreads();
    if (lane == 0) {
        float mx = s2[0];
#pragma unroll
        for (int c = 1; c < 6; ++c) mx = fmaxf(mx, s2[c]);
        float se = 0.f;
#pragma unroll
        for (int c = 0; c < 6; ++c) se += __expf(s2[c] - mx);
        float lse = mx + __logf(se);
#pragma unroll
        for (int c = 0; c < 6; ++c) out[g * 6 + c] = s2[c] - lse;
    }
}

extern "C" void kernel_launch(void* const* d_in, const int* in_sizes, int n_in,
                              void* d_out, int out_size, void* d_ws, size_t ws_size,
                              hipStream_t stream) {
    const float* x    = (const float*)d_in[0];
    const int* ei     = (const int*)d_in[1];
    const int* batch  = (const int*)d_in[2];
    const float* W    = (const float*)d_in[3];
    const float* wih  = (const float*)d_in[4];
    const float* whh  = (const float*)d_in[5];
    const float* bih  = (const float*)d_in[6];
    const float* bhh  = (const float*)d_in[7];
    const float* fc1w = (const float*)d_in[8];
    const float* fc1b = (const float*)d_in[9];
    const float* fc2w = (const float*)d_in[10];
    const float* fc2b = (const float*)d_in[11];
    float* out = (float*)d_out;

    // ---- workspace layout ----
    float* h      = (float*)d_ws;               // 3.2M f
    float* m      = h + N_NODES * D1;           // 3.2M f
    float* pooled = m + N_NODES * D1;           // 8192 f
    float* bias4  = pooled + N_GRAPHS * D1;     // 256 f
    int* deg      = (int*)(bias4 + 256);        // N_NODES
    u16* srcidx   = (u16*)(deg + N_NODES);      // N_NODES*CAP u16 = 6.4 MB
    size_t soff = ((size_t)(srcidx + N_NODES * CAP) + 15) & ~(size_t)15;
    short* hhi  = (short*)soff;                 // 3.2M
    short* hlo  = hhi + N_NODES * D1;
    short* Bh   = hlo + N_NODES * D1;           // 32768
    short* Bl   = Bh + 32768;
    short* Wh   = Bl + 32768;                   // 8192 (2 layers x 4096)
    short* Wl   = Wh + 8192;

    // ---- bucketed, XCD-sliced CSR build ----
    hipMemsetAsync(deg, 0, N_NODES * sizeof(int), stream);
    fill_kernel<<<NSLICE * 32, 256, 0, stream>>>(ei, deg, srcidx);

    // ---- fused weight packing ----
    pack_all_kernel<<<161, 256, 0, stream>>>(wih, whh, W, bih, bhh, Bh, Bl, Wh, Wl, bias4);

    const int GB = (N_NODES + 63) / 64;  // 782
    // layer 0: read x as f32, split in-register
    mm_mfma<true><<<GB, 256, 0, stream>>>(x, nullptr, nullptr, Wh, Wl, m);
    gruagg_mfma<true><<<GB, 256, 0, stream>>>(m, deg, srcidx, x, hhi, hlo, Bh, Bl, bias4, h);
    // layer 1: h in bf16 hi/lo (written by gru0 epilogue)
    mm_mfma<false><<<GB, 256, 0, stream>>>(nullptr, hhi, hlo, Wh + 4096, Wl + 4096, m);
    gruagg_mfma<false><<<GB, 256, 0, stream>>>(m, deg, srcidx, h, hhi, hlo, Bh, Bl, bias4, h);

    pool_kernel<<<N_GRAPHS, 256, 0, stream>>>(h, batch, pooled);
    head_kernel<<<N_GRAPHS, 64, 0, stream>>>(pooled, fc1w, fc1b, fc2w, fc2b, out);
}

// Round 8
// 370.980 us; speedup vs baseline: 1.3904x; 1.3904x over previous
//
#include <hip/hip_runtime.h>

#define N_NODES 50000
#define N_EDGES 800000
#define D1 64
#define D2 32
#define N_CLASSES 6
#define N_GRAPHS 128
#define CAP 64      // per-node src bucket capacity; deg ~ Binom(800k,1/50k) mean 16, max ~45
#define NSLICE 16
#define SLICEN (N_NODES / NSLICE)   // 3125
#define ECHUNK (N_EDGES / 32)       // 25000

typedef unsigned short u16;
typedef __attribute__((ext_vector_type(8))) short bf16x8;
typedef __attribute__((ext_vector_type(4))) float f32x4;

__device__ __forceinline__ float bf2f(u16 b) {
    unsigned int u = ((unsigned int)b) << 16;
    float f;
    __builtin_memcpy(&f, &u, 4);
    return f;
}
__device__ __forceinline__ u16 f2bf(float f) {
    unsigned int u;
    __builtin_memcpy(&u, &f, 4);
    unsigned int r = (u + 0x7fffu + ((u >> 16) & 1u)) >> 16;
    return (u16)r;
}
__device__ __forceinline__ void split8(const float* v, bf16x8& hi, bf16x8& lo) {
#pragma unroll
    for (int j = 0; j < 8; ++j) {
        u16 h = f2bf(v[j]);
        hi[j] = (short)h;
        lo[j] = (short)f2bf(v[j] - bf2f(h));
    }
}
__device__ __forceinline__ float sigmoidf_(float x) {
    return 1.0f / (1.0f + __expf(-x));
}
__device__ __forceinline__ float tanhf_(float x) {
    return 1.0f - 2.0f / (__expf(2.0f * x) + 1.0f);
}

// ============ XCD-sliced bucketed fill (deg pre-zeroed via memset) ============
__global__ __launch_bounds__(256) void fill_kernel(const int* __restrict__ ei,
                                                   int* __restrict__ deg,
                                                   u16* __restrict__ srcidx) {
    int slice = blockIdx.x & 15;
    int chunk = blockIdx.x >> 4;  // 0..31
    int lo = slice * SLICEN, hi = lo + SLICEN;
    const int* dstp = ei + N_EDGES + chunk * ECHUNK;
    const int* srcp = ei + chunk * ECHUNK;
    for (int i = threadIdx.x; i < ECHUNK; i += 256) {
        int d = dstp[i];
        if (d >= lo && d < hi) {
            int p = atomicAdd(&deg[d], 1);
            if (p < CAP) srcidx[d * CAP + p] = (u16)srcp[i];
        }
    }
}

// ================= fused weight packing =================
__global__ __launch_bounds__(256) void pack_all_kernel(const float* __restrict__ wih,
                                                       const float* __restrict__ whh,
                                                       const float* __restrict__ W,
                                                       const float* __restrict__ bih,
                                                       const float* __restrict__ bhh,
                                                       short* __restrict__ Bh,
                                                       short* __restrict__ Bl,
                                                       short* __restrict__ Wh,
                                                       short* __restrict__ Wl,
                                                       float* __restrict__ bias4) {
    int b = blockIdx.x;
    if (b < 128) {
        int idx = b * 256 + threadIdx.x;
        int j = idx & 7;
        int lane = (idx >> 3) & 63;
        int nt = (idx >> 9) & 15;
        int kt = idx >> 13;
        int k = kt * 32 + (lane >> 4) * 8 + j;
        int n = nt * 16 + (lane & 15);
        int g = n >> 6, d = n & 63;
        float v;
        if (g == 0)      v = (k < 64) ? wih[d * 64 + k] : whh[d * 64 + (k - 64)];
        else if (g == 1) v = (k < 64) ? wih[(64 + d) * 64 + k] : whh[(64 + d) * 64 + (k - 64)];
        else if (g == 2) v = (k < 64) ? wih[(128 + d) * 64 + k] : 0.f;
        else             v = (k < 64) ? 0.f : whh[(128 + d) * 64 + (k - 64)];
        u16 hi = f2bf(v);
        Bh[idx] = (short)hi;
        Bl[idx] = (short)f2bf(v - bf2f(hi));
    } else if (b < 160) {
        int idx = (b - 128) * 256 + threadIdx.x;
        int j = idx & 7;
        int lane = (idx >> 3) & 63;
        int nt = (idx >> 9) & 3;
        int kt = (idx >> 11) & 1;
        int L = idx >> 12;
        int k = kt * 32 + (lane >> 4) * 8 + j;
        int n = nt * 16 + (lane & 15);
        float v = W[L * 4096 + k * 64 + n];
        u16 hi = f2bf(v);
        Wh[idx] = (short)hi;
        Wl[idx] = (short)f2bf(v - bf2f(hi));
    } else {
        int j = threadIdx.x;
        if (j < 64) {
            bias4[j] = bih[j] + bhh[j];
            bias4[64 + j] = bih[64 + j] + bhh[64 + j];
            bias4[128 + j] = bih[128 + j];
            bias4[192 + j] = bhh[128 + j];
        }
    }
}

// ================= MFMA GEMMs =================
// m = hin @ W_L. L0: A from x (f32, split in-register); else from hhi/hlo.
template <bool L0>
__global__ __launch_bounds__(256) void mm_mfma(const float* __restrict__ xf,
                                               const short* __restrict__ Ahi,
                                               const short* __restrict__ Alo,
                                               const short* __restrict__ Wh,
                                               const short* __restrict__ Wl,
                                               float* __restrict__ m) {
    int lane = threadIdx.x & 63;
    int wv = threadIdx.x >> 6;
    int node0 = blockIdx.x * 64 + wv * 16;
    if (node0 >= N_NODES) return;
    int c0 = lane & 15, qr = lane >> 4;

    f32x4 acc[4];
#pragma unroll
    for (int nt = 0; nt < 4; ++nt) acc[nt] = (f32x4){0.f, 0.f, 0.f, 0.f};

#pragma unroll
    for (int kt = 0; kt < 2; ++kt) {
        int aoff = (node0 + c0) * 64 + kt * 32 + qr * 8;
        bf16x8 ah, al;
        if (L0) {
            float tmp[8];
#pragma unroll
            for (int j = 0; j < 8; ++j) tmp[j] = xf[aoff + j];
            split8(tmp, ah, al);
        } else {
            ah = *(const bf16x8*)(Ahi + aoff);
            al = *(const bf16x8*)(Alo + aoff);
        }
#pragma unroll
        for (int nt = 0; nt < 4; ++nt) {
            int boff = (kt * 4 + nt) * 512 + lane * 8;
            bf16x8 bh = *(const bf16x8*)(Wh + boff);
            bf16x8 bl = *(const bf16x8*)(Wl + boff);
            acc[nt] = __builtin_amdgcn_mfma_f32_16x16x32_bf16(ah, bh, acc[nt], 0, 0, 0);
            acc[nt] = __builtin_amdgcn_mfma_f32_16x16x32_bf16(ah, bl, acc[nt], 0, 0, 0);
            acc[nt] = __builtin_amdgcn_mfma_f32_16x16x32_bf16(al, bh, acc[nt], 0, 0, 0);
        }
    }
#pragma unroll
    for (int nt = 0; nt < 4; ++nt)
#pragma unroll
        for (int r = 0; r < 4; ++r)
            m[(node0 + qr * 4 + r) * 64 + nt * 16 + c0] = acc[nt][r];
}

// ===== agg: wave per node (50k waves for MLP), lane = feature; bf16-split output =====
__global__ __launch_bounds__(256) void agg_kernel(const float* __restrict__ m,
                                                  const int* __restrict__ deg,
                                                  const u16* __restrict__ srcidx,
                                                  short* __restrict__ aghi,
                                                  short* __restrict__ aglo) {
    int lane = threadIdx.x & 63;
    int wv = threadIdx.x >> 6;
    int node = blockIdx.x * 4 + wv;  // grid exact: 50000/4
    int cnt = __builtin_amdgcn_readfirstlane(deg[node]);
    cnt = cnt < CAP ? cnt : CAP;
    const u16* bucket = srcidx + node * CAP;
    float acc = 0.f;
    int k = 0;
    for (; k + 4 <= cnt; k += 4) {
        int s0 = __builtin_amdgcn_readfirstlane((int)bucket[k]);
        int s1 = __builtin_amdgcn_readfirstlane((int)bucket[k + 1]);
        int s2 = __builtin_amdgcn_readfirstlane((int)bucket[k + 2]);
        int s3 = __builtin_amdgcn_readfirstlane((int)bucket[k + 3]);
        acc += m[s0 * 64 + lane];
        acc += m[s1 * 64 + lane];
        acc += m[s2 * 64 + lane];
        acc += m[s3 * 64 + lane];
    }
    for (; k < cnt; ++k) {
        int s = __builtin_amdgcn_readfirstlane((int)bucket[k]);
        acc += m[s * 64 + lane];
    }
    u16 hi = f2bf(acc);
    aghi[node * 64 + lane] = (short)hi;
    aglo[node * 64 + lane] = (short)f2bf(acc - bf2f(hi));
}

// ===== GRU as GEMM + fused gates + fused bf16 split of h_out =====
template <bool L0>
__global__ __launch_bounds__(256) void gru_mfma(const short* __restrict__ aghi,
                                                const short* __restrict__ aglo,
                                                short* hhi, short* hlo,
                                                const short* __restrict__ Bh,
                                                const short* __restrict__ Bl,
                                                const float* __restrict__ bias4,
                                                const float* __restrict__ hin,  // x (L0) or h f32
                                                float* __restrict__ hout) {
    int lane = threadIdx.x & 63;
    int wv = threadIdx.x >> 6;
    int node0 = blockIdx.x * 64 + wv * 16;
    if (node0 >= N_NODES) return;
    int c0 = lane & 15, qr = lane >> 4;

    f32x4 acc[16];
#pragma unroll
    for (int nt = 0; nt < 16; ++nt) acc[nt] = (f32x4){0.f, 0.f, 0.f, 0.f};

#pragma unroll
    for (int kt = 0; kt < 4; ++kt) {
        bf16x8 ah, al;
        int aoff = (node0 + c0) * 64 + (kt & 1) * 32 + qr * 8;
        if (kt < 2) {
            ah = *(const bf16x8*)(aghi + aoff);
            al = *(const bf16x8*)(aglo + aoff);
        } else if (L0) {  // h half = x, split in-register
            float tmp[8];
#pragma unroll
            for (int j = 0; j < 8; ++j) tmp[j] = hin[aoff + j];
            split8(tmp, ah, al);
        } else {
            ah = *(const bf16x8*)(hhi + aoff);
            al = *(const bf16x8*)(hlo + aoff);
        }
#pragma unroll
        for (int nt = 0; nt < 16; ++nt) {
            int boff = (kt * 16 + nt) * 512 + lane * 8;
            bf16x8 bh = *(const bf16x8*)(Bh + boff);
            bf16x8 bl = *(const bf16x8*)(Bl + boff);
            acc[nt] = __builtin_amdgcn_mfma_f32_16x16x32_bf16(ah, bh, acc[nt], 0, 0, 0);
            acc[nt] = __builtin_amdgcn_mfma_f32_16x16x32_bf16(ah, bl, acc[nt], 0, 0, 0);
            acc[nt] = __builtin_amdgcn_mfma_f32_16x16x32_bf16(al, bh, acc[nt], 0, 0, 0);
        }
    }

    // gates: cols j, 64+j, 128+j, 192+j live in n-tiles jt, jt+4, jt+8, jt+12
#pragma unroll
    for (int r = 0; r < 4; ++r) {
        int row = node0 + qr * 4 + r;
#pragma unroll
        for (int jt = 0; jt < 4; ++jt) {
            int j = jt * 16 + c0;
            float rr = sigmoidf_(acc[jt][r] + bias4[j]);
            float zz = sigmoidf_(acc[4 + jt][r] + bias4[64 + j]);
            float nn = tanhf_(acc[8 + jt][r] + bias4[128 + j] +
                              rr * (acc[12 + jt][r] + bias4[192 + j]));
            float ho = hin[row * 64 + j];
            float v = (1.f - zz) * nn + zz * ho;
            hout[row * 64 + j] = v;
            u16 hi = f2bf(v);
            hhi[row * 64 + j] = (short)hi;
            hlo[row * 64 + j] = (short)f2bf(v - bf2f(hi));
        }
    }
}

// relu + segment-mean pool
__global__ __launch_bounds__(256) void pool_kernel(const float* __restrict__ h,
                                                   const int* __restrict__ batch,
                                                   float* __restrict__ pooled) {
    int g = blockIdx.x;
    int tid = threadIdx.x, lane = tid & 63, wv = tid >> 6;
    int lo, hi;
    {
        int a = 0, b = N_NODES;
        while (a < b) { int mid = (a + b) >> 1; if (batch[mid] < g) a = mid + 1; else b = mid; }
        lo = a;
    }
    {
        int a = lo, b = N_NODES;
        while (a < b) { int mid = (a + b) >> 1; if (batch[mid] < g + 1) a = mid + 1; else b = mid; }
        hi = a;
    }
    float acc = 0.f;
    for (int n = lo + wv; n < hi; n += 4) acc += fmaxf(h[n * 64 + lane], 0.f);
    __shared__ float red[4][64];
    red[wv][lane] = acc;
    __syncthreads();
    if (wv == 0) {
        float s = red[0][lane] + red[1][lane] + red[2][lane] + red[3][lane];
        float cnt = (float)(hi - lo);
        pooled[g * 64 + lane] = s / fmaxf(cnt, 1.f);
    }
}

// head: fc1+relu, fc2, log_softmax
__global__ __launch_bounds__(64) void head_kernel(const float* __restrict__ pooled,
                                                  const float* __restrict__ fc1w,
                                                  const float* __restrict__ fc1b,
                                                  const float* __restrict__ fc2w,
                                                  const float* __restrict__ fc2b,
                                                  float* __restrict__ out) {
    int g = blockIdx.x;
    int lane = threadIdx.x;
    __shared__ float pv[64];
    __shared__ float s1[32];
    __shared__ float s2[6];
    pv[lane] = pooled[g * 64 + lane];
    __syncthreads();
    if (lane < 32) {
        float acc = fc1b[lane];
#pragma unroll
        for (int j = 0; j < 64; ++j) acc = fmaf(pv[j], fc1w[lane * 64 + j], acc);
        s1[lane] = fmaxf(acc, 0.f);
    }
    __syncthreads();
    if (lane < 6) {
        float acc = fc2b[lane];
#pragma unroll
        for (int j = 0; j < 32; ++j) acc = fmaf(s1[j], fc2w[lane * 32 + j], acc);
        s2[lane] = acc;
    }
    __syncthreads();
    if (lane == 0) {
        float mx = s2[0];
#pragma unroll
        for (int c = 1; c < 6; ++c) mx = fmaxf(mx, s2[c]);
        float se = 0.f;
#pragma unroll
        for (int c = 0; c < 6; ++c) se += __expf(s2[c] - mx);
        float lse = mx + __logf(se);
#pragma unroll
        for (int c = 0; c < 6; ++c) out[g * 6 + c] = s2[c] - lse;
    }
}

extern "C" void kernel_launch(void* const* d_in, const int* in_sizes, int n_in,
                              void* d_out, int out_size, void* d_ws, size_t ws_size,
                              hipStream_t stream) {
    const float* x    = (const float*)d_in[0];
    const int* ei     = (const int*)d_in[1];
    const int* batch  = (const int*)d_in[2];
    const float* W    = (const float*)d_in[3];
    const float* wih  = (const float*)d_in[4];
    const float* whh  = (const float*)d_in[5];
    const float* bih  = (const float*)d_in[6];
    const float* bhh  = (const float*)d_in[7];
    const float* fc1w = (const float*)d_in[8];
    const float* fc1b = (const float*)d_in[9];
    const float* fc2w = (const float*)d_in[10];
    const float* fc2b = (const float*)d_in[11];
    float* out = (float*)d_out;

    // ---- workspace layout ----
    float* h      = (float*)d_ws;               // 3.2M f
    float* m      = h + N_NODES * D1;           // 3.2M f
    float* pooled = m + N_NODES * D1;           // 8192 f
    float* bias4  = pooled + N_GRAPHS * D1;     // 256 f
    int* deg      = (int*)(bias4 + 256);        // N_NODES
    u16* srcidx   = (u16*)(deg + N_NODES);      // N_NODES*CAP u16 = 6.4 MB
    size_t soff = ((size_t)(srcidx + N_NODES * CAP) + 15) & ~(size_t)15;
    short* hhi  = (short*)soff;                 // 3.2M
    short* hlo  = hhi + N_NODES * D1;
    short* aghi = hlo + N_NODES * D1;
    short* aglo = aghi + N_NODES * D1;
    short* Bh   = aglo + N_NODES * D1;          // 32768
    short* Bl   = Bh + 32768;
    short* Wh   = Bl + 32768;                   // 8192 (2 layers x 4096)
    short* Wl   = Wh + 8192;

    // ---- bucketed, XCD-sliced CSR build ----
    hipMemsetAsync(deg, 0, N_NODES * sizeof(int), stream);
    fill_kernel<<<NSLICE * 32, 256, 0, stream>>>(ei, deg, srcidx);

    // ---- fused weight packing ----
    pack_all_kernel<<<161, 256, 0, stream>>>(wih, whh, W, bih, bhh, Bh, Bl, Wh, Wl, bias4);

    const int GB = (N_NODES + 63) / 64;  // 782
    // layer 0 (x read as f32, split in-register)
    mm_mfma<true><<<GB, 256, 0, stream>>>(x, nullptr, nullptr, Wh, Wl, m);
    agg_kernel<<<N_NODES / 4, 256, 0, stream>>>(m, deg, srcidx, aghi, aglo);
    gru_mfma<true><<<GB, 256, 0, stream>>>(aghi, aglo, hhi, hlo, Bh, Bl, bias4, x, h);
    // layer 1 (h in bf16 hi/lo from gru0 epilogue)
    mm_mfma<false><<<GB, 256, 0, stream>>>(nullptr, hhi, hlo, Wh + 4096, Wl + 4096, m);
    agg_kernel<<<N_NODES / 4, 256, 0, stream>>>(m, deg, srcidx, aghi, aglo);
    gru_mfma<false><<<GB, 256, 0, stream>>>(aghi, aglo, hhi, hlo, Bh, Bl, bias4, h, h);

    pool_kernel<<<N_GRAPHS, 256, 0, stream>>>(h, batch, pooled);
    head_kernel<<<N_GRAPHS, 64, 0, stream>>>(pooled, fc1w, fc1b, fc2w, fc2b, out);
}

// Round 9
// 327.740 us; speedup vs baseline: 1.5738x; 1.1319x over previous
//
#include <hip/hip_runtime.h>

#define N_NODES 50000
#define N_EDGES 800000
#define D1 64
#define D2 32
#define N_CLASSES 6
#define N_GRAPHS 128
#define CAP 64      // per-node src bucket capacity; deg ~ Binom(800k,1/50k) mean 16, max ~45

typedef unsigned short u16;
typedef __attribute__((ext_vector_type(8))) short bf16x8;
typedef __attribute__((ext_vector_type(4))) float f32x4;

__device__ __forceinline__ float bf2f(u16 b) {
    unsigned int u = ((unsigned int)b) << 16;
    float f;
    __builtin_memcpy(&f, &u, 4);
    return f;
}
__device__ __forceinline__ u16 f2bf(float f) {
    unsigned int u;
    __builtin_memcpy(&u, &f, 4);
    unsigned int r = (u + 0x7fffu + ((u >> 16) & 1u)) >> 16;
    return (u16)r;
}
__device__ __forceinline__ void split8(const float* v, bf16x8& hi, bf16x8& lo) {
#pragma unroll
    for (int j = 0; j < 8; ++j) {
        u16 h = f2bf(v[j]);
        hi[j] = (short)h;
        lo[j] = (short)f2bf(v[j] - bf2f(h));
    }
}
__device__ __forceinline__ float sigmoidf_(float x) {
    return 1.0f / (1.0f + __expf(-x));
}
__device__ __forceinline__ float tanhf_(float x) {
    return 1.0f - 2.0f / (__expf(2.0f * x) + 1.0f);
}

// ============ bucketed fill: one edge per thread (deg pre-zeroed via memset) ============
// r8 lesson: XCD-sliced 16x-scan variant was 2x SLOWER (under-parallelized). Keep simple.
__global__ __launch_bounds__(256) void fill_kernel(const int* __restrict__ ei,
                                                   int* __restrict__ deg,
                                                   u16* __restrict__ srcidx) {
    int e = blockIdx.x * 256 + threadIdx.x;  // grid exact: 800000/256 = 3125
    int d = ei[N_EDGES + e];
    int s = ei[e];
    int p = atomicAdd(&deg[d], 1);
    if (p < CAP) srcidx[d * CAP + p] = (u16)s;
}

// ================= fused weight packing =================
__global__ __launch_bounds__(256) void pack_all_kernel(const float* __restrict__ wih,
                                                       const float* __restrict__ whh,
                                                       const float* __restrict__ W,
                                                       const float* __restrict__ bih,
                                                       const float* __restrict__ bhh,
                                                       short* __restrict__ Bh,
                                                       short* __restrict__ Bl,
                                                       short* __restrict__ Wh,
                                                       short* __restrict__ Wl,
                                                       float* __restrict__ bias4) {
    int b = blockIdx.x;
    if (b < 128) {
        int idx = b * 256 + threadIdx.x;
        int j = idx & 7;
        int lane = (idx >> 3) & 63;
        int nt = (idx >> 9) & 15;
        int kt = idx >> 13;
        int k = kt * 32 + (lane >> 4) * 8 + j;
        int n = nt * 16 + (lane & 15);
        int g = n >> 6, d = n & 63;
        float v;
        if (g == 0)      v = (k < 64) ? wih[d * 64 + k] : whh[d * 64 + (k - 64)];
        else if (g == 1) v = (k < 64) ? wih[(64 + d) * 64 + k] : whh[(64 + d) * 64 + (k - 64)];
        else if (g == 2) v = (k < 64) ? wih[(128 + d) * 64 + k] : 0.f;
        else             v = (k < 64) ? 0.f : whh[(128 + d) * 64 + (k - 64)];
        u16 hi = f2bf(v);
        Bh[idx] = (short)hi;
        Bl[idx] = (short)f2bf(v - bf2f(hi));
    } else if (b < 160) {
        int idx = (b - 128) * 256 + threadIdx.x;
        int j = idx & 7;
        int lane = (idx >> 3) & 63;
        int nt = (idx >> 9) & 3;
        int kt = (idx >> 11) & 1;
        int L = idx >> 12;
        int k = kt * 32 + (lane >> 4) * 8 + j;
        int n = nt * 16 + (lane & 15);
        float v = W[L * 4096 + k * 64 + n];
        u16 hi = f2bf(v);
        Wh[idx] = (short)hi;
        Wl[idx] = (short)f2bf(v - bf2f(hi));
    } else {
        int j = threadIdx.x;
        if (j < 64) {
            bias4[j] = bih[j] + bhh[j];
            bias4[64 + j] = bih[64 + j] + bhh[64 + j];
            bias4[128 + j] = bih[128 + j];
            bias4[192 + j] = bhh[128 + j];
        }
    }
}

// ================= MFMA GEMMs =================
// m = hin @ W_L, output stored as bf16 (m only feeds the agg sum; rounding noise
// is averaged down by the 390-node mean pool). L0: A from x f32 split in-register.
template <bool L0>
__global__ __launch_bounds__(256) void mm_mfma(const float* __restrict__ xf,
                                               const short* __restrict__ Ahi,
                                               const short* __restrict__ Alo,
                                               const short* __restrict__ Wh,
                                               const short* __restrict__ Wl,
                                               u16* __restrict__ m16) {
    int lane = threadIdx.x & 63;
    int wv = threadIdx.x >> 6;
    int node0 = blockIdx.x * 64 + wv * 16;
    if (node0 >= N_NODES) return;
    int c0 = lane & 15, qr = lane >> 4;

    f32x4 acc[4];
#pragma unroll
    for (int nt = 0; nt < 4; ++nt) acc[nt] = (f32x4){0.f, 0.f, 0.f, 0.f};

#pragma unroll
    for (int kt = 0; kt < 2; ++kt) {
        int aoff = (node0 + c0) * 64 + kt * 32 + qr * 8;
        bf16x8 ah, al;
        if (L0) {
            float tmp[8];
#pragma unroll
            for (int j = 0; j < 8; ++j) tmp[j] = xf[aoff + j];
            split8(tmp, ah, al);
        } else {
            ah = *(const bf16x8*)(Ahi + aoff);
            al = *(const bf16x8*)(Alo + aoff);
        }
#pragma unroll
        for (int nt = 0; nt < 4; ++nt) {
            int boff = (kt * 4 + nt) * 512 + lane * 8;
            bf16x8 bh = *(const bf16x8*)(Wh + boff);
            bf16x8 bl = *(const bf16x8*)(Wl + boff);
            acc[nt] = __builtin_amdgcn_mfma_f32_16x16x32_bf16(ah, bh, acc[nt], 0, 0, 0);
            acc[nt] = __builtin_amdgcn_mfma_f32_16x16x32_bf16(ah, bl, acc[nt], 0, 0, 0);
            acc[nt] = __builtin_amdgcn_mfma_f32_16x16x32_bf16(al, bh, acc[nt], 0, 0, 0);
        }
    }
#pragma unroll
    for (int nt = 0; nt < 4; ++nt)
#pragma unroll
        for (int r = 0; r < 4; ++r)
            m16[(node0 + qr * 4 + r) * 64 + nt * 16 + c0] = f2bf(acc[nt][r]);
}

// ===== agg: wave per node (50k waves for MLP), lane = feature; bf16-split output =====
__global__ __launch_bounds__(256) void agg_kernel(const u16* __restrict__ m16,
                                                  const int* __restrict__ deg,
                                                  const u16* __restrict__ srcidx,
                                                  short* __restrict__ aghi,
                                                  short* __restrict__ aglo) {
    int lane = threadIdx.x & 63;
    int wv = threadIdx.x >> 6;
    int node = blockIdx.x * 4 + wv;  // grid exact: 50000/4
    int cnt = __builtin_amdgcn_readfirstlane(deg[node]);
    cnt = cnt < CAP ? cnt : CAP;
    const u16* bucket = srcidx + node * CAP;
    float acc = 0.f;
    int k = 0;
    for (; k + 4 <= cnt; k += 4) {
        int s0 = __builtin_amdgcn_readfirstlane((int)bucket[k]);
        int s1 = __builtin_amdgcn_readfirstlane((int)bucket[k + 1]);
        int s2 = __builtin_amdgcn_readfirstlane((int)bucket[k + 2]);
        int s3 = __builtin_amdgcn_readfirstlane((int)bucket[k + 3]);
        acc += bf2f(m16[s0 * 64 + lane]);
        acc += bf2f(m16[s1 * 64 + lane]);
        acc += bf2f(m16[s2 * 64 + lane]);
        acc += bf2f(m16[s3 * 64 + lane]);
    }
    for (; k < cnt; ++k) {
        int s = __builtin_amdgcn_readfirstlane((int)bucket[k]);
        acc += bf2f(m16[s * 64 + lane]);
    }
    u16 hi = f2bf(acc);
    aghi[node * 64 + lane] = (short)hi;
    aglo[node * 64 + lane] = (short)f2bf(acc - bf2f(hi));
}

// ===== GRU as GEMM + fused gates + fused bf16 split of h_out =====
template <bool L0>
__global__ __launch_bounds__(256) void gru_mfma(const short* __restrict__ aghi,
                                                const short* __restrict__ aglo,
                                                short* hhi, short* hlo,
                                                const short* __restrict__ Bh,
                                                const short* __restrict__ Bl,
                                                const float* __restrict__ bias4,
                                                const float* __restrict__ hin,  // x (L0) or h f32
                                                float* __restrict__ hout) {
    int lane = threadIdx.x & 63;
    int wv = threadIdx.x >> 6;
    int node0 = blockIdx.x * 64 + wv * 16;
    if (node0 >= N_NODES) return;
    int c0 = lane & 15, qr = lane >> 4;

    f32x4 acc[16];
#pragma unroll
    for (int nt = 0; nt < 16; ++nt) acc[nt] = (f32x4){0.f, 0.f, 0.f, 0.f};

#pragma unroll
    for (int kt = 0; kt < 4; ++kt) {
        bf16x8 ah, al;
        int aoff = (node0 + c0) * 64 + (kt & 1) * 32 + qr * 8;
        if (kt < 2) {
            ah = *(const bf16x8*)(aghi + aoff);
            al = *(const bf16x8*)(aglo + aoff);
        } else if (L0) {  // h half = x, split in-register
            float tmp[8];
#pragma unroll
            for (int j = 0; j < 8; ++j) tmp[j] = hin[aoff + j];
            split8(tmp, ah, al);
        } else {
            ah = *(const bf16x8*)(hhi + aoff);
            al = *(const bf16x8*)(hlo + aoff);
        }
#pragma unroll
        for (int nt = 0; nt < 16; ++nt) {
            int boff = (kt * 16 + nt) * 512 + lane * 8;
            bf16x8 bh = *(const bf16x8*)(Bh + boff);
            bf16x8 bl = *(const bf16x8*)(Bl + boff);
            acc[nt] = __builtin_amdgcn_mfma_f32_16x16x32_bf16(ah, bh, acc[nt], 0, 0, 0);
            acc[nt] = __builtin_amdgcn_mfma_f32_16x16x32_bf16(ah, bl, acc[nt], 0, 0, 0);
            acc[nt] = __builtin_amdgcn_mfma_f32_16x16x32_bf16(al, bh, acc[nt], 0, 0, 0);
        }
    }

    // gates: cols j, 64+j, 128+j, 192+j live in n-tiles jt, jt+4, jt+8, jt+12
#pragma unroll
    for (int r = 0; r < 4; ++r) {
        int row = node0 + qr * 4 + r;
#pragma unroll
        for (int jt = 0; jt < 4; ++jt) {
            int j = jt * 16 + c0;
            float rr = sigmoidf_(acc[jt][r] + bias4[j]);
            float zz = sigmoidf_(acc[4 + jt][r] + bias4[64 + j]);
            float nn = tanhf_(acc[8 + jt][r] + bias4[128 + j] +
                              rr * (acc[12 + jt][r] + bias4[192 + j]));
            float ho = hin[row * 64 + j];
            float v = (1.f - zz) * nn + zz * ho;
            hout[row * 64 + j] = v;
            u16 hi = f2bf(v);
            hhi[row * 64 + j] = (short)hi;
            hlo[row * 64 + j] = (short)f2bf(v - bf2f(hi));
        }
    }
}

// relu + segment-mean pool
__global__ __launch_bounds__(256) void pool_kernel(const float* __restrict__ h,
                                                   const int* __restrict__ batch,
                                                   float* __restrict__ pooled) {
    int g = blockIdx.x;
    int tid = threadIdx.x, lane = tid & 63, wv = tid >> 6;
    int lo, hi;
    {
        int a = 0, b = N_NODES;
        while (a < b) { int mid = (a + b) >> 1; if (batch[mid] < g) a = mid + 1; else b = mid; }
        lo = a;
    }
    {
        int a = lo, b = N_NODES;
        while (a < b) { int mid = (a + b) >> 1; if (batch[mid] < g + 1) a = mid + 1; else b = mid; }
        hi = a;
    }
    float acc = 0.f;
    for (int n = lo + wv; n < hi; n += 4) acc += fmaxf(h[n * 64 + lane], 0.f);
    __shared__ float red[4][64];
    red[wv][lane] = acc;
    __syncthreads();
    if (wv == 0) {
        float s = red[0][lane] + red[1][lane] + red[2][lane] + red[3][lane];
        float cnt = (float)(hi - lo);
        pooled[g * 64 + lane] = s / fmaxf(cnt, 1.f);
    }
}

// head: fc1+relu, fc2, log_softmax
__global__ __launch_bounds__(64) void head_kernel(const float* __restrict__ pooled,
                                                  const float* __restrict__ fc1w,
                                                  const float* __restrict__ fc1b,
                                                  const float* __restrict__ fc2w,
                                                  const float* __restrict__ fc2b,
                                                  float* __restrict__ out) {
    int g = blockIdx.x;
    int lane = threadIdx.x;
    __shared__ float pv[64];
    __shared__ float s1[32];
    __shared__ float s2[6];
    pv[lane] = pooled[g * 64 + lane];
    __syncthreads();
    if (lane < 32) {
        float acc = fc1b[lane];
#pragma unroll
        for (int j = 0; j < 64; ++j) acc = fmaf(pv[j], fc1w[lane * 64 + j], acc);
        s1[lane] = fmaxf(acc, 0.f);
    }
    __syncthreads();
    if (lane < 6) {
        float acc = fc2b[lane];
#pragma unroll
        for (int j = 0; j < 32; ++j) acc = fmaf(s1[j], fc2w[lane * 32 + j], acc);
        s2[lane] = acc;
    }
    __syncthreads();
    if (lane == 0) {
        float mx = s2[0];
#pragma unroll
        for (int c = 1; c < 6; ++c) mx = fmaxf(mx, s2[c]);
        float se = 0.f;
#pragma unroll
        for (int c = 0; c < 6; ++c) se += __expf(s2[c] - mx);
        float lse = mx + __logf(se);
#pragma unroll
        for (int c = 0; c < 6; ++c) out[g * 6 + c] = s2[c] - lse;
    }
}

extern "C" void kernel_launch(void* const* d_in, const int* in_sizes, int n_in,
                              void* d_out, int out_size, void* d_ws, size_t ws_size,
                              hipStream_t stream) {
    const float* x    = (const float*)d_in[0];
    const int* ei     = (const int*)d_in[1];
    const int* batch  = (const int*)d_in[2];
    const float* W    = (const float*)d_in[3];
    const float* wih  = (const float*)d_in[4];
    const float* whh  = (const float*)d_in[5];
    const float* bih  = (const float*)d_in[6];
    const float* bhh  = (const float*)d_in[7];
    const float* fc1w = (const float*)d_in[8];
    const float* fc1b = (const float*)d_in[9];
    const float* fc2w = (const float*)d_in[10];
    const float* fc2b = (const float*)d_in[11];
    float* out = (float*)d_out;

    // ---- workspace layout ----
    float* h      = (float*)d_ws;               // 3.2M f
    float* pooled = h + N_NODES * D1;           // 8192 f
    float* bias4  = pooled + N_GRAPHS * D1;     // 256 f
    int* deg      = (int*)(bias4 + 256);        // N_NODES
    u16* srcidx   = (u16*)(deg + N_NODES);      // N_NODES*CAP u16 = 6.4 MB
    size_t soff = ((size_t)(srcidx + N_NODES * CAP) + 15) & ~(size_t)15;
    u16* m16    = (u16*)soff;                   // 3.2M u16 (bf16 m)
    short* hhi  = (short*)(m16 + N_NODES * D1); // 3.2M
    short* hlo  = hhi + N_NODES * D1;
    short* aghi = hlo + N_NODES * D1;
    short* aglo = aghi + N_NODES * D1;
    short* Bh   = aglo + N_NODES * D1;          // 32768
    short* Bl   = Bh + 32768;
    short* Wh   = Bl + 32768;                   // 8192 (2 layers x 4096)
    short* Wl   = Wh + 8192;

    // ---- bucketed CSR build ----
    hipMemsetAsync(deg, 0, N_NODES * sizeof(int), stream);
    fill_kernel<<<N_EDGES / 256, 256, 0, stream>>>(ei, deg, srcidx);

    // ---- fused weight packing ----
    pack_all_kernel<<<161, 256, 0, stream>>>(wih, whh, W, bih, bhh, Bh, Bl, Wh, Wl, bias4);

    const int GB = (N_NODES + 63) / 64;  // 782
    // layer 0 (x read as f32, split in-register)
    mm_mfma<true><<<GB, 256, 0, stream>>>(x, nullptr, nullptr, Wh, Wl, m16);
    agg_kernel<<<N_NODES / 4, 256, 0, stream>>>(m16, deg, srcidx, aghi, aglo);
    gru_mfma<true><<<GB, 256, 0, stream>>>(aghi, aglo, hhi, hlo, Bh, Bl, bias4, x, h);
    // layer 1 (h in bf16 hi/lo from gru0 epilogue)
    mm_mfma<false><<<GB, 256, 0, stream>>>(nullptr, hhi, hlo, Wh + 4096, Wl + 4096, m16);
    agg_kernel<<<N_NODES / 4, 256, 0, stream>>>(m16, deg, srcidx, aghi, aglo);
    gru_mfma<false><<<GB, 256, 0, stream>>>(aghi, aglo, hhi, hlo, Bh, Bl, bias4, h, h);

    pool_kernel<<<N_GRAPHS, 256, 0, stream>>>(h, batch, pooled);
    head_kernel<<<N_GRAPHS, 64, 0, stream>>>(pooled, fc1w, fc1b, fc2w, fc2b, out);
}

// Round 10
// 316.814 us; speedup vs baseline: 1.6281x; 1.0345x over previous
//
#include <hip/hip_runtime.h>

#define N_NODES 50000
#define N_EDGES 800000
#define D1 64
#define D2 32
#define N_CLASSES 6
#define N_GRAPHS 128
#define CAP 64      // per-node src bucket capacity == wave size; deg max ~45 << 64
#define GB 782      // ceil(50000/64) blocks for 64-row GEMM tiles

typedef unsigned short u16;
typedef __attribute__((ext_vector_type(8))) short bf16x8;
typedef __attribute__((ext_vector_type(4))) float f32x4;

__device__ __forceinline__ float bf2f(u16 b) {
    unsigned int u = ((unsigned int)b) << 16;
    float f;
    __builtin_memcpy(&f, &u, 4);
    return f;
}
__device__ __forceinline__ u16 f2bf(float f) {
    unsigned int u;
    __builtin_memcpy(&u, &f, 4);
    unsigned int r = (u + 0x7fffu + ((u >> 16) & 1u)) >> 16;
    return (u16)r;
}
__device__ __forceinline__ void split8(const float* v, bf16x8& hi, bf16x8& lo) {
#pragma unroll
    for (int j = 0; j < 8; ++j) {
        u16 h = f2bf(v[j]);
        hi[j] = (short)h;
        lo[j] = (short)f2bf(v[j] - bf2f(h));
    }
}
__device__ __forceinline__ float sigmoidf_(float x) {
    return 1.0f / (1.0f + __expf(-x));
}
__device__ __forceinline__ float tanhf_(float x) {
    return 1.0f - 2.0f / (__expf(2.0f * x) + 1.0f);
}

// ===== fused: mm L0 (blocks 0..781) + B/bias pack (782..910) + fill (911..4035) =====
// All three are mutually independent; fill (~50us) is the long pole, mm/pack hide under it.
__global__ __launch_bounds__(256) void fused_head_kernel(
        const int* __restrict__ ei, int* __restrict__ deg, u16* __restrict__ srcidx,
        const float* __restrict__ x, const float* __restrict__ W,
        const float* __restrict__ wih, const float* __restrict__ whh,
        const float* __restrict__ bih, const float* __restrict__ bhh,
        short* __restrict__ Bh, short* __restrict__ Bl, float* __restrict__ bias4,
        u16* __restrict__ m16) {
    int b = blockIdx.x;
    int tid = threadIdx.x;
    if (b < GB) {
        // ---- mm L0: m = x @ W0, raw f32 W (16 KB, L1-resident), split in-register ----
        int lane = tid & 63;
        int wv = tid >> 6;
        int node0 = b * 64 + wv * 16;
        if (node0 >= N_NODES) return;
        int c0 = lane & 15, qr = lane >> 4;
        f32x4 acc[4];
#pragma unroll
        for (int nt = 0; nt < 4; ++nt) acc[nt] = (f32x4){0.f, 0.f, 0.f, 0.f};
#pragma unroll
        for (int kt = 0; kt < 2; ++kt) {
            int aoff = (node0 + c0) * 64 + kt * 32 + qr * 8;
            float tmp[8];
#pragma unroll
            for (int j = 0; j < 8; ++j) tmp[j] = x[aoff + j];
            bf16x8 ah, al;
            split8(tmp, ah, al);
            int k0 = kt * 32 + qr * 8;
#pragma unroll
            for (int nt = 0; nt < 4; ++nt) {
                int n = nt * 16 + c0;
                float wt[8];
#pragma unroll
                for (int j = 0; j < 8; ++j) wt[j] = W[(k0 + j) * 64 + n];
                bf16x8 bh, bl;
                split8(wt, bh, bl);
                acc[nt] = __builtin_amdgcn_mfma_f32_16x16x32_bf16(ah, bh, acc[nt], 0, 0, 0);
                acc[nt] = __builtin_amdgcn_mfma_f32_16x16x32_bf16(ah, bl, acc[nt], 0, 0, 0);
                acc[nt] = __builtin_amdgcn_mfma_f32_16x16x32_bf16(al, bh, acc[nt], 0, 0, 0);
            }
        }
#pragma unroll
        for (int nt = 0; nt < 4; ++nt)
#pragma unroll
            for (int r = 0; r < 4; ++r)
                m16[(node0 + qr * 4 + r) * 64 + nt * 16 + c0] = f2bf(acc[nt][r]);
    } else if (b < GB + 128) {
        // ---- pack GRU B in fragment order ----
        int idx = (b - GB) * 256 + tid;
        int j = idx & 7;
        int lane = (idx >> 3) & 63;
        int nt = (idx >> 9) & 15;
        int kt = idx >> 13;
        int k = kt * 32 + (lane >> 4) * 8 + j;
        int n = nt * 16 + (lane & 15);
        int g = n >> 6, d = n & 63;
        float v;
        if (g == 0)      v = (k < 64) ? wih[d * 64 + k] : whh[d * 64 + (k - 64)];
        else if (g == 1) v = (k < 64) ? wih[(64 + d) * 64 + k] : whh[(64 + d) * 64 + (k - 64)];
        else if (g == 2) v = (k < 64) ? wih[(128 + d) * 64 + k] : 0.f;
        else             v = (k < 64) ? 0.f : whh[(128 + d) * 64 + (k - 64)];
        u16 hi = f2bf(v);
        Bh[idx] = (short)hi;
        Bl[idx] = (short)f2bf(v - bf2f(hi));
    } else if (b == GB + 128) {
        int j = tid;
        if (j < 64) {
            bias4[j] = bih[j] + bhh[j];
            bias4[64 + j] = bih[64 + j] + bhh[64 + j];
            bias4[128 + j] = bih[128 + j];
            bias4[192 + j] = bhh[128 + j];
        }
    } else {
        // ---- bucketed fill: one edge per thread (deg pre-zeroed via memset) ----
        int e = (b - GB - 129) * 256 + tid;  // exact: 3125 blocks
        int d = ei[N_EDGES + e];
        int s = ei[e];
        int p = atomicAdd(&deg[d], 1);
        if (p < CAP) srcidx[d * CAP + p] = (u16)s;
    }
}

// ===== mm L1: m = h @ W1, A from hhi/hlo, raw f32 W =====
__global__ __launch_bounds__(256) void mm_mfma(const short* __restrict__ Ahi,
                                               const short* __restrict__ Alo,
                                               const float* __restrict__ Wf,
                                               u16* __restrict__ m16) {
    int lane = threadIdx.x & 63;
    int wv = threadIdx.x >> 6;
    int node0 = blockIdx.x * 64 + wv * 16;
    if (node0 >= N_NODES) return;
    int c0 = lane & 15, qr = lane >> 4;
    f32x4 acc[4];
#pragma unroll
    for (int nt = 0; nt < 4; ++nt) acc[nt] = (f32x4){0.f, 0.f, 0.f, 0.f};
#pragma unroll
    for (int kt = 0; kt < 2; ++kt) {
        int aoff = (node0 + c0) * 64 + kt * 32 + qr * 8;
        bf16x8 ah = *(const bf16x8*)(Ahi + aoff);
        bf16x8 al = *(const bf16x8*)(Alo + aoff);
        int k0 = kt * 32 + qr * 8;
#pragma unroll
        for (int nt = 0; nt < 4; ++nt) {
            int n = nt * 16 + c0;
            float wt[8];
#pragma unroll
            for (int j = 0; j < 8; ++j) wt[j] = Wf[(k0 + j) * 64 + n];
            bf16x8 bh, bl;
            split8(wt, bh, bl);
            acc[nt] = __builtin_amdgcn_mfma_f32_16x16x32_bf16(ah, bh, acc[nt], 0, 0, 0);
            acc[nt] = __builtin_amdgcn_mfma_f32_16x16x32_bf16(ah, bl, acc[nt], 0, 0, 0);
            acc[nt] = __builtin_amdgcn_mfma_f32_16x16x32_bf16(al, bh, acc[nt], 0, 0, 0);
        }
    }
#pragma unroll
    for (int nt = 0; nt < 4; ++nt)
#pragma unroll
        for (int r = 0; r < 4; ++r)
            m16[(node0 + qr * 4 + r) * 64 + nt * 16 + c0] = f2bf(acc[nt][r]);
}

// ===== agg: wave per node; bucket loaded ONCE (bucket[lane], CAP==64) and
// broadcast per-edge via shfl -> no serial scalar-load chain. =====
__global__ __launch_bounds__(256) void agg_kernel(const u16* __restrict__ m16,
                                                  const int* __restrict__ deg,
                                                  const u16* __restrict__ srcidx,
                                                  short* __restrict__ aghi,
                                                  short* __restrict__ aglo) {
    int lane = threadIdx.x & 63;
    int wv = threadIdx.x >> 6;
    int node = blockIdx.x * 4 + wv;  // grid exact: 50000/4
    int cnt = __builtin_amdgcn_readfirstlane(deg[node]);
    cnt = cnt < CAP ? cnt : CAP;
    int bv = (int)srcidx[node * CAP + lane];  // one coalesced 128B row
    float acc = 0.f;
    int k = 0;
    for (; k + 4 <= cnt; k += 4) {
        int s0 = __shfl(bv, k);
        int s1 = __shfl(bv, k + 1);
        int s2 = __shfl(bv, k + 2);
        int s3 = __shfl(bv, k + 3);
        acc += bf2f(m16[s0 * 64 + lane]);
        acc += bf2f(m16[s1 * 64 + lane]);
        acc += bf2f(m16[s2 * 64 + lane]);
        acc += bf2f(m16[s3 * 64 + lane]);
    }
    for (; k < cnt; ++k) {
        int s = __shfl(bv, k);
        acc += bf2f(m16[s * 64 + lane]);
    }
    u16 hi = f2bf(acc);
    aghi[node * 64 + lane] = (short)hi;
    aglo[node * 64 + lane] = (short)f2bf(acc - bf2f(hi));
}

// ===== GRU GEMM + gates; B staged per-kt in LDS (32 KB) shared by 4 waves =====
template <bool L0>
__global__ __launch_bounds__(256) void gru_mfma(const short* __restrict__ aghi,
                                                const short* __restrict__ aglo,
                                                short* hhi, short* hlo,
                                                const short* __restrict__ Bh,
                                                const short* __restrict__ Bl,
                                                const float* __restrict__ bias4,
                                                const float* __restrict__ hin,  // x (L0) or h f32
                                                float* __restrict__ hout) {
    __shared__ short Bhs[8192];  // 16 KB: one kt slab of Bh
    __shared__ short Bls[8192];  // 16 KB
    int tid = threadIdx.x;
    int lane = tid & 63;
    int wv = tid >> 6;
    int node0 = blockIdx.x * 64 + wv * 16;
    // clamp instead of early-return (barriers below); duplicated rows write identical values
    if (node0 > N_NODES - 16) node0 = N_NODES - 16;  // N_NODES % 16 == 0
    int c0 = lane & 15, qr = lane >> 4;

    f32x4 acc[16];
#pragma unroll
    for (int nt = 0; nt < 16; ++nt) acc[nt] = (f32x4){0.f, 0.f, 0.f, 0.f};

#pragma unroll
    for (int kt = 0; kt < 4; ++kt) {
        __syncthreads();  // protect previous slab reads
        {
            const float4* sH = (const float4*)(Bh + kt * 8192);
            const float4* sL = (const float4*)(Bl + kt * 8192);
            float4* dH = (float4*)Bhs;
            float4* dL = (float4*)Bls;
            for (int i = tid; i < 1024; i += 256) {
                dH[i] = sH[i];
                dL[i] = sL[i];
            }
        }
        __syncthreads();

        bf16x8 ah, al;
        int aoff = (node0 + c0) * 64 + (kt & 1) * 32 + qr * 8;
        if (kt < 2) {
            ah = *(const bf16x8*)(aghi + aoff);
            al = *(const bf16x8*)(aglo + aoff);
        } else if (L0) {  // h half = x, split in-register
            float tmp[8];
#pragma unroll
            for (int j = 0; j < 8; ++j) tmp[j] = hin[aoff + j];
            split8(tmp, ah, al);
        } else {
            ah = *(const bf16x8*)(hhi + aoff);
            al = *(const bf16x8*)(hlo + aoff);
        }
#pragma unroll
        for (int nt = 0; nt < 16; ++nt) {
            bf16x8 bh = *(const bf16x8*)(Bhs + nt * 512 + lane * 8);
            bf16x8 bl = *(const bf16x8*)(Bls + nt * 512 + lane * 8);
            acc[nt] = __builtin_amdgcn_mfma_f32_16x16x32_bf16(ah, bh, acc[nt], 0, 0, 0);
            acc[nt] = __builtin_amdgcn_mfma_f32_16x16x32_bf16(ah, bl, acc[nt], 0, 0, 0);
            acc[nt] = __builtin_amdgcn_mfma_f32_16x16x32_bf16(al, bh, acc[nt], 0, 0, 0);
        }
    }

    // gates: cols j, 64+j, 128+j, 192+j live in n-tiles jt, jt+4, jt+8, jt+12
#pragma unroll
    for (int r = 0; r < 4; ++r) {
        int row = node0 + qr * 4 + r;
#pragma unroll
        for (int jt = 0; jt < 4; ++jt) {
            int j = jt * 16 + c0;
            float rr = sigmoidf_(acc[jt][r] + bias4[j]);
            float zz = sigmoidf_(acc[4 + jt][r] + bias4[64 + j]);
            float nn = tanhf_(acc[8 + jt][r] + bias4[128 + j] +
                              rr * (acc[12 + jt][r] + bias4[192 + j]));
            float ho = hin[row * 64 + j];
            float v = (1.f - zz) * nn + zz * ho;
            hout[row * 64 + j] = v;
            u16 hi = f2bf(v);
            hhi[row * 64 + j] = (short)hi;
            hlo[row * 64 + j] = (short)f2bf(v - bf2f(hi));
        }
    }
}

// relu + segment-mean pool
__global__ __launch_bounds__(256) void pool_kernel(const float* __restrict__ h,
                                                   const int* __restrict__ batch,
                                                   float* __restrict__ pooled) {
    int g = blockIdx.x;
    int tid = threadIdx.x, lane = tid & 63, wv = tid >> 6;
    int lo, hi;
    {
        int a = 0, b = N_NODES;
        while (a < b) { int mid = (a + b) >> 1; if (batch[mid] < g) a = mid + 1; else b = mid; }
        lo = a;
    }
    {
        int a = lo, b = N_NODES;
        while (a < b) { int mid = (a + b) >> 1; if (batch[mid] < g + 1) a = mid + 1; else b = mid; }
        hi = a;
    }
    float acc = 0.f;
    for (int n = lo + wv; n < hi; n += 4) acc += fmaxf(h[n * 64 + lane], 0.f);
    __shared__ float red[4][64];
    red[wv][lane] = acc;
    __syncthreads();
    if (wv == 0) {
        float s = red[0][lane] + red[1][lane] + red[2][lane] + red[3][lane];
        float cnt = (float)(hi - lo);
        pooled[g * 64 + lane] = s / fmaxf(cnt, 1.f);
    }
}

// head: fc1+relu, fc2, log_softmax
__global__ __launch_bounds__(64) void head_kernel(const float* __restrict__ pooled,
                                                  const float* __restrict__ fc1w,
                                                  const float* __restrict__ fc1b,
                                                  const float* __restrict__ fc2w,
                                                  const float* __restrict__ fc2b,
                                                  float* __restrict__ out) {
    int g = blockIdx.x;
    int lane = threadIdx.x;
    __shared__ float pv[64];
    __shared__ float s1[32];
    __shared__ float s2[6];
    pv[lane] = pooled[g * 64 + lane];
    __syncthreads();
    if (lane < 32) {
        float acc = fc1b[lane];
#pragma unroll
        for (int j = 0; j < 64; ++j) acc = fmaf(pv[j], fc1w[lane * 64 + j], acc);
        s1[lane] = fmaxf(acc, 0.f);
    }
    __syncthreads();
    if (lane < 6) {
        float acc = fc2b[lane];
#pragma unroll
        for (int j = 0; j < 32; ++j) acc = fmaf(s1[j], fc2w[lane * 32 + j], acc);
        s2[lane] = acc;
    }
    __syncthreads();
    if (lane == 0) {
        float mx = s2[0];
#pragma unroll
        for (int c = 1; c < 6; ++c) mx = fmaxf(mx, s2[c]);
        float se = 0.f;
#pragma unroll
        for (int c = 0; c < 6; ++c) se += __expf(s2[c] - mx);
        float lse = mx + __logf(se);
#pragma unroll
        for (int c = 0; c < 6; ++c) out[g * 6 + c] = s2[c] - lse;
    }
}

extern "C" void kernel_launch(void* const* d_in, const int* in_sizes, int n_in,
                              void* d_out, int out_size, void* d_ws, size_t ws_size,
                              hipStream_t stream) {
    const float* x    = (const float*)d_in[0];
    const int* ei     = (const int*)d_in[1];
    const int* batch  = (const int*)d_in[2];
    const float* W    = (const float*)d_in[3];
    const float* wih  = (const float*)d_in[4];
    const float* whh  = (const float*)d_in[5];
    const float* bih  = (const float*)d_in[6];
    const float* bhh  = (const float*)d_in[7];
    const float* fc1w = (const float*)d_in[8];
    const float* fc1b = (const float*)d_in[9];
    const float* fc2w = (const float*)d_in[10];
    const float* fc2b = (const float*)d_in[11];
    float* out = (float*)d_out;

    // ---- workspace layout ----
    float* h      = (float*)d_ws;               // 3.2M f
    float* pooled = h + N_NODES * D1;           // 8192 f
    float* bias4  = pooled + N_GRAPHS * D1;     // 256 f
    int* deg      = (int*)(bias4 + 256);        // N_NODES
    u16* srcidx   = (u16*)(deg + N_NODES);      // N_NODES*CAP u16 = 6.4 MB
    size_t soff = ((size_t)(srcidx + N_NODES * CAP) + 15) & ~(size_t)15;
    u16* m16    = (u16*)soff;                   // 3.2M u16 (bf16 m)
    short* hhi  = (short*)(m16 + N_NODES * D1); // 3.2M
    short* hlo  = hhi + N_NODES * D1;
    short* aghi = hlo + N_NODES * D1;
    short* aglo = aghi + N_NODES * D1;
    short* Bh   = aglo + N_NODES * D1;          // 32768
    short* Bl   = Bh + 32768;

    hipMemsetAsync(deg, 0, N_NODES * sizeof(int), stream);
    // fused: mm L0 + B/bias pack + fill (fill is the long pole; rest hides under it)
    fused_head_kernel<<<GB + 129 + N_EDGES / 256, 256, 0, stream>>>(
        ei, deg, srcidx, x, W, wih, whh, bih, bhh, Bh, Bl, bias4, m16);

    // layer 0
    agg_kernel<<<N_NODES / 4, 256, 0, stream>>>(m16, deg, srcidx, aghi, aglo);
    gru_mfma<true><<<GB, 256, 0, stream>>>(aghi, aglo, hhi, hlo, Bh, Bl, bias4, x, h);
    // layer 1
    mm_mfma<<<GB, 256, 0, stream>>>(hhi, hlo, W + 4096, m16);
    agg_kernel<<<N_NODES / 4, 256, 0, stream>>>(m16, deg, srcidx, aghi, aglo);
    gru_mfma<false><<<GB, 256, 0, stream>>>(aghi, aglo, hhi, hlo, Bh, Bl, bias4, h, h);

    pool_kernel<<<N_GRAPHS, 256, 0, stream>>>(h, batch, pooled);
    head_kernel<<<N_GRAPHS, 64, 0, stream>>>(pooled, fc1w, fc1b, fc2w, fc2b, out);
}

// Round 11
// 291.240 us; speedup vs baseline: 1.7710x; 1.0878x over previous
//
#include <hip/hip_runtime.h>

#define N_NODES 50000
#define N_EDGES 800000
#define D1 64
#define D2 32
#define N_CLASSES 6
#define N_GRAPHS 128
#define CAP 64       // per-node src bucket capacity == wave size; deg max ~45 << 64
#define GB 782       // ceil(50000/64)
#define NFB 3125     // N_EDGES/256 fill blocks

typedef unsigned short u16;
typedef unsigned int u32;
typedef __attribute__((ext_vector_type(8))) short bf16x8;
typedef __attribute__((ext_vector_type(4))) float f32x4;

__device__ __forceinline__ float bf2f(u16 b) {
    u32 u = ((u32)b) << 16;
    float f;
    __builtin_memcpy(&f, &u, 4);
    return f;
}
__device__ __forceinline__ u16 f2bf(float f) {
    u32 u;
    __builtin_memcpy(&u, &f, 4);
    u32 r = (u + 0x7fffu + ((u >> 16) & 1u)) >> 16;
    return (u16)r;
}
__device__ __forceinline__ void split8(const float* v, bf16x8& hi, bf16x8& lo) {
#pragma unroll
    for (int j = 0; j < 8; ++j) {
        u16 h = f2bf(v[j]);
        hi[j] = (short)h;
        lo[j] = (short)f2bf(v[j] - bf2f(h));
    }
}
__device__ __forceinline__ float sigmoidf_(float x) {
    return 1.0f / (1.0f + __expf(-x));
}
__device__ __forceinline__ float tanhf_(float x) {
    return 1.0f - 2.0f / (__expf(2.0f * x) + 1.0f);
}

// ===== fused: fill (blocks 0..3124, FIRST: latency-bound, frees issue slots)
//        + B/bias pack (3125..3253) + mm L0 (3254..4035, compute-bound backfill) =====
__global__ __launch_bounds__(256) void fused_head_kernel(
        const int* __restrict__ ei, int* __restrict__ deg, u16* __restrict__ srcidx,
        const float* __restrict__ x, const float* __restrict__ W,
        const float* __restrict__ wih, const float* __restrict__ whh,
        const float* __restrict__ bih, const float* __restrict__ bhh,
        short* __restrict__ Bh, short* __restrict__ Bl, float* __restrict__ bias4,
        u16* __restrict__ m16) {
    int b = blockIdx.x;
    int tid = threadIdx.x;
    if (b < NFB) {
        // ---- bucketed fill: one edge per thread (deg pre-zeroed via memset) ----
        int e = b * 256 + tid;
        int d = ei[N_EDGES + e];
        int s = ei[e];
        int p = atomicAdd(&deg[d], 1);
        if (p < CAP) srcidx[d * CAP + p] = (u16)s;
    } else if (b < NFB + 128) {
        // ---- pack GRU B in fragment order ----
        int idx = (b - NFB) * 256 + tid;
        int j = idx & 7;
        int lane = (idx >> 3) & 63;
        int nt = (idx >> 9) & 15;
        int kt = idx >> 13;
        int k = kt * 32 + (lane >> 4) * 8 + j;
        int n = nt * 16 + (lane & 15);
        int g = n >> 6, d = n & 63;
        float v;
        if (g == 0)      v = (k < 64) ? wih[d * 64 + k] : whh[d * 64 + (k - 64)];
        else if (g == 1) v = (k < 64) ? wih[(64 + d) * 64 + k] : whh[(64 + d) * 64 + (k - 64)];
        else if (g == 2) v = (k < 64) ? wih[(128 + d) * 64 + k] : 0.f;
        else             v = (k < 64) ? 0.f : whh[(128 + d) * 64 + (k - 64)];
        u16 hi = f2bf(v);
        Bh[idx] = (short)hi;
        Bl[idx] = (short)f2bf(v - bf2f(hi));
    } else if (b == NFB + 128) {
        int j = tid;
        if (j < 64) {
            bias4[j] = bih[j] + bhh[j];
            bias4[64 + j] = bih[64 + j] + bhh[64 + j];
            bias4[128 + j] = bih[128 + j];
            bias4[192 + j] = bhh[128 + j];
        }
    } else {
        // ---- mm L0: m = x @ W0, raw f32 W (16 KB, L1-resident), split in-register ----
        int lane = tid & 63;
        int wv = tid >> 6;
        int node0 = (b - NFB - 129) * 64 + wv * 16;
        if (node0 >= N_NODES) return;
        int c0 = lane & 15, qr = lane >> 4;
        f32x4 acc[4];
#pragma unroll
        for (int nt = 0; nt < 4; ++nt) acc[nt] = (f32x4){0.f, 0.f, 0.f, 0.f};
#pragma unroll
        for (int kt = 0; kt < 2; ++kt) {
            int aoff = (node0 + c0) * 64 + kt * 32 + qr * 8;
            float tmp[8];
#pragma unroll
            for (int j = 0; j < 8; ++j) tmp[j] = x[aoff + j];
            bf16x8 ah, al;
            split8(tmp, ah, al);
            int k0 = kt * 32 + qr * 8;
#pragma unroll
            for (int nt = 0; nt < 4; ++nt) {
                int n = nt * 16 + c0;
                float wt[8];
#pragma unroll
                for (int j = 0; j < 8; ++j) wt[j] = W[(k0 + j) * 64 + n];
                bf16x8 bh, bl;
                split8(wt, bh, bl);
                acc[nt] = __builtin_amdgcn_mfma_f32_16x16x32_bf16(ah, bh, acc[nt], 0, 0, 0);
                acc[nt] = __builtin_amdgcn_mfma_f32_16x16x32_bf16(ah, bl, acc[nt], 0, 0, 0);
                acc[nt] = __builtin_amdgcn_mfma_f32_16x16x32_bf16(al, bh, acc[nt], 0, 0, 0);
            }
        }
#pragma unroll
        for (int nt = 0; nt < 4; ++nt)
#pragma unroll
            for (int r = 0; r < 4; ++r)
                m16[(node0 + qr * 4 + r) * 64 + nt * 16 + c0] = f2bf(acc[nt][r]);
    }
}

// ===== agg: wave per node; half-wave dword gather (2 edges in flight, 4B/lane) =====
__global__ __launch_bounds__(256) void agg_kernel(const u16* __restrict__ m16,
                                                  const int* __restrict__ deg,
                                                  const u16* __restrict__ srcidx,
                                                  short* __restrict__ aghi,
                                                  short* __restrict__ aglo) {
    int lane = threadIdx.x & 63;
    int wv = threadIdx.x >> 6;
    int node = blockIdx.x * 4 + wv;  // grid exact: 50000/4
    int cnt = __builtin_amdgcn_readfirstlane(deg[node]);
    cnt = cnt < CAP ? cnt : CAP;
    int bv = (int)srcidx[node * CAP + lane];  // bucket, one coalesced 128B row
    int half = lane >> 5;                     // 0: even edges, 1: odd edges
    int l = lane & 31;                        // dword index: features 2l, 2l+1
    const u32* m32 = (const u32*)m16;
    float a0 = 0.f, a1 = 0.f;
    int k = half;
    for (; k + 6 < cnt; k += 8) {
        int s0 = __shfl(bv, k);
        int s1 = __shfl(bv, k + 2);
        int s2 = __shfl(bv, k + 4);
        int s3 = __shfl(bv, k + 6);
        u32 d0 = m32[s0 * 32 + l];
        u32 d1 = m32[s1 * 32 + l];
        u32 d2 = m32[s2 * 32 + l];
        u32 d3 = m32[s3 * 32 + l];
        a0 += bf2f((u16)d0) + bf2f((u16)d1) + bf2f((u16)d2) + bf2f((u16)d3);
        a1 += bf2f((u16)(d0 >> 16)) + bf2f((u16)(d1 >> 16)) +
              bf2f((u16)(d2 >> 16)) + bf2f((u16)(d3 >> 16));
    }
    for (; k < cnt; k += 2) {
        int s = __shfl(bv, k);
        u32 d = m32[s * 32 + l];
        a0 += bf2f((u16)d);
        a1 += bf2f((u16)(d >> 16));
    }
    // combine the two half-wave partials
    a0 += __shfl_xor(a0, 32);
    a1 += __shfl_xor(a1, 32);
    if (half == 0) {
        u16 h0 = f2bf(a0), h1 = f2bf(a1);
        u16 g0 = f2bf(a0 - bf2f(h0)), g1 = f2bf(a1 - bf2f(h1));
        ((u32*)aghi)[node * 32 + l] = (u32)h0 | ((u32)h1 << 16);
        ((u32*)aglo)[node * 32 + l] = (u32)g0 | ((u32)g1 << 16);
    }
}

// ===== GRU GEMM + gates; B staged per-kt in LDS; optional fused mm (next layer)
//       via per-wave LDS transpose reusing the B slabs; LAST skips hhi/hlo. =====
template <bool L0, bool DO_MM, bool LAST>
__global__ __launch_bounds__(256) void gru_mfma(const short* __restrict__ aghi,
                                                const short* __restrict__ aglo,
                                                short* hhi, short* hlo,
                                                const short* __restrict__ Bh,
                                                const short* __restrict__ Bl,
                                                const float* __restrict__ bias4,
                                                const float* __restrict__ hin,  // x (L0) or h f32
                                                float* __restrict__ hout,
                                                const float* __restrict__ Wnext,
                                                u16* __restrict__ m16) {
    __shared__ short Bhs[8192];  // 16 KB slab; reused as transpose tile after K-loop
    __shared__ short Bls[8192];
    int tid = threadIdx.x;
    int lane = tid & 63;
    int wv = tid >> 6;
    int node0 = blockIdx.x * 64 + wv * 16;
    // clamp (barriers below); duplicated rows write identical values
    if (node0 > N_NODES - 16) node0 = N_NODES - 16;
    int c0 = lane & 15, qr = lane >> 4;

    f32x4 acc[16];
#pragma unroll
    for (int nt = 0; nt < 16; ++nt) acc[nt] = (f32x4){0.f, 0.f, 0.f, 0.f};

#pragma unroll
    for (int kt = 0; kt < 4; ++kt) {
        __syncthreads();  // protect previous slab reads
        {
            const float4* sH = (const float4*)(Bh + kt * 8192);
            const float4* sL = (const float4*)(Bl + kt * 8192);
            float4* dH = (float4*)Bhs;
            float4* dL = (float4*)Bls;
            for (int i = tid; i < 1024; i += 256) {
                dH[i] = sH[i];
                dL[i] = sL[i];
            }
        }
        __syncthreads();

        bf16x8 ah, al;
        int aoff = (node0 + c0) * 64 + (kt & 1) * 32 + qr * 8;
        if (kt < 2) {
            ah = *(const bf16x8*)(aghi + aoff);
            al = *(const bf16x8*)(aglo + aoff);
        } else if (L0) {  // h half = x, split in-register
            float tmp[8];
#pragma unroll
            for (int j = 0; j < 8; ++j) tmp[j] = hin[aoff + j];
            split8(tmp, ah, al);
        } else {
            ah = *(const bf16x8*)(hhi + aoff);
            al = *(const bf16x8*)(hlo + aoff);
        }
#pragma unroll
        for (int nt = 0; nt < 16; ++nt) {
            bf16x8 bh = *(const bf16x8*)(Bhs + nt * 512 + lane * 8);
            bf16x8 bl = *(const bf16x8*)(Bls + nt * 512 + lane * 8);
            acc[nt] = __builtin_amdgcn_mfma_f32_16x16x32_bf16(ah, bh, acc[nt], 0, 0, 0);
            acc[nt] = __builtin_amdgcn_mfma_f32_16x16x32_bf16(ah, bl, acc[nt], 0, 0, 0);
            acc[nt] = __builtin_amdgcn_mfma_f32_16x16x32_bf16(al, bh, acc[nt], 0, 0, 0);
        }
    }
    if (DO_MM) __syncthreads();  // all waves done reading B slabs before tile reuse

    // per-wave transpose tile (16 rows x 65 floats, 4160 B): waves 0,1 in Bhs; 2,3 in Bls
    float* myTile = (float*)(wv < 2 ? Bhs : Bls) + (wv & 1) * 1040;

    // gates: cols j, 64+j, 128+j, 192+j live in n-tiles jt, jt+4, jt+8, jt+12
#pragma unroll
    for (int r = 0; r < 4; ++r) {
        int row = node0 + qr * 4 + r;
#pragma unroll
        for (int jt = 0; jt < 4; ++jt) {
            int j = jt * 16 + c0;
            float rr = sigmoidf_(acc[jt][r] + bias4[j]);
            float zz = sigmoidf_(acc[4 + jt][r] + bias4[64 + j]);
            float nn = tanhf_(acc[8 + jt][r] + bias4[128 + j] +
                              rr * (acc[12 + jt][r] + bias4[192 + j]));
            float ho = hin[row * 64 + j];
            float v = (1.f - zz) * nn + zz * ho;
            hout[row * 64 + j] = v;
            if (!LAST) {
                u16 hi = f2bf(v);
                hhi[row * 64 + j] = (short)hi;
                hlo[row * 64 + j] = (short)f2bf(v - bf2f(hi));
            }
            if (DO_MM) myTile[(qr * 4 + r) * 65 + j] = v;
        }
    }

    if (DO_MM) {
        // mm next layer: m16[row] = h[row] @ Wnext; A from wave-local tile
        f32x4 macc[4];
#pragma unroll
        for (int nt = 0; nt < 4; ++nt) macc[nt] = (f32x4){0.f, 0.f, 0.f, 0.f};
#pragma unroll
        for (int kt = 0; kt < 2; ++kt) {
            float tmp[8];
            int k0 = kt * 32 + qr * 8;
#pragma unroll
            for (int j = 0; j < 8; ++j) tmp[j] = myTile[c0 * 65 + k0 + j];
            bf16x8 ah, al;
            split8(tmp, ah, al);
#pragma unroll
            for (int nt = 0; nt < 4; ++nt) {
                int n = nt * 16 + c0;
                float wt[8];
#pragma unroll
                for (int j = 0; j < 8; ++j) wt[j] = Wnext[(k0 + j) * 64 + n];
                bf16x8 bh, bl;
                split8(wt, bh, bl);
                macc[nt] = __builtin_amdgcn_mfma_f32_16x16x32_bf16(ah, bh, macc[nt], 0, 0, 0);
                macc[nt] = __builtin_amdgcn_mfma_f32_16x16x32_bf16(ah, bl, macc[nt], 0, 0, 0);
                macc[nt] = __builtin_amdgcn_mfma_f32_16x16x32_bf16(al, bh, macc[nt], 0, 0, 0);
            }
        }
#pragma unroll
        for (int nt = 0; nt < 4; ++nt)
#pragma unroll
            for (int r = 0; r < 4; ++r)
                m16[(node0 + qr * 4 + r) * 64 + nt * 16 + c0] = f2bf(macc[nt][r]);
    }
}

// relu + segment-mean partial sums: 4 chunks per graph (512 blocks)
__global__ __launch_bounds__(256) void pool_kernel(const float* __restrict__ h,
                                                   const int* __restrict__ batch,
                                                   float* __restrict__ pooledp) {
    int g = blockIdx.x >> 2, c = blockIdx.x & 3;
    int tid = threadIdx.x, lane = tid & 63, wv = tid >> 6;
    int lo, hi;
    {
        int a = 0, b = N_NODES;
        while (a < b) { int mid = (a + b) >> 1; if (batch[mid] < g) a = mid + 1; else b = mid; }
        lo = a;
    }
    {
        int a = lo, b = N_NODES;
        while (a < b) { int mid = (a + b) >> 1; if (batch[mid] < g + 1) a = mid + 1; else b = mid; }
        hi = a;
    }
    int len = hi - lo;
    int start = lo + (len * c) / 4;
    int end = lo + (len * (c + 1)) / 4;
    float acc = 0.f;
    for (int n = start + wv; n < end; n += 4) acc += fmaxf(h[n * 64 + lane], 0.f);
    __shared__ float red[4][64];
    red[wv][lane] = acc;
    __syncthreads();
    if (wv == 0) {
        pooledp[(g * 4 + c) * 64 + lane] =
            red[0][lane] + red[1][lane] + red[2][lane] + red[3][lane];
    }
}

// head: sum partials, mean, fc1+relu, fc2, log_softmax
__global__ __launch_bounds__(64) void head_kernel(const float* __restrict__ pooledp,
                                                  const int* __restrict__ batch,
                                                  const float* __restrict__ fc1w,
                                                  const float* __restrict__ fc1b,
                                                  const float* __restrict__ fc2w,
                                                  const float* __restrict__ fc2b,
                                                  float* __restrict__ out) {
    int g = blockIdx.x;
    int lane = threadIdx.x;
    __shared__ float pv[64];
    __shared__ float s1[32];
    __shared__ float s2[6];
    int lo, hi;
    {
        int a = 0, b = N_NODES;
        while (a < b) { int mid = (a + b) >> 1; if (batch[mid] < g) a = mid + 1; else b = mid; }
        lo = a;
    }
    {
        int a = lo, b = N_NODES;
        while (a < b) { int mid = (a + b) >> 1; if (batch[mid] < g + 1) a = mid + 1; else b = mid; }
        hi = a;
    }
    float s = pooledp[(g * 4 + 0) * 64 + lane] + pooledp[(g * 4 + 1) * 64 + lane] +
              pooledp[(g * 4 + 2) * 64 + lane] + pooledp[(g * 4 + 3) * 64 + lane];
    pv[lane] = s / fmaxf((float)(hi - lo), 1.f);
    __syncthreads();
    if (lane < 32) {
        float acc = fc1b[lane];
#pragma unroll
        for (int j = 0; j < 64; ++j) acc = fmaf(pv[j], fc1w[lane * 64 + j], acc);
        s1[lane] = fmaxf(acc, 0.f);
    }
    __syncthreads();
    if (lane < 6) {
        float acc = fc2b[lane];
#pragma unroll
        for (int j = 0; j < 32; ++j) acc = fmaf(s1[j], fc2w[lane * 32 + j], acc);
        s2[lane] = acc;
    }
    __syncthreads();
    if (lane == 0) {
        float mx = s2[0];
#pragma unroll
        for (int c = 1; c < 6; ++c) mx = fmaxf(mx, s2[c]);
        float se = 0.f;
#pragma unroll
        for (int c = 0; c < 6; ++c) se += __expf(s2[c] - mx);
        float lse = mx + __logf(se);
#pragma unroll
        for (int c = 0; c < 6; ++c) out[g * 6 + c] = s2[c] - lse;
    }
}

extern "C" void kernel_launch(void* const* d_in, const int* in_sizes, int n_in,
                              void* d_out, int out_size, void* d_ws, size_t ws_size,
                              hipStream_t stream) {
    const float* x    = (const float*)d_in[0];
    const int* ei     = (const int*)d_in[1];
    const int* batch  = (const int*)d_in[2];
    const float* W    = (const float*)d_in[3];
    const float* wih  = (const float*)d_in[4];
    const float* whh  = (const float*)d_in[5];
    const float* bih  = (const float*)d_in[6];
    const float* bhh  = (const float*)d_in[7];
    const float* fc1w = (const float*)d_in[8];
    const float* fc1b = (const float*)d_in[9];
    const float* fc2w = (const float*)d_in[10];
    const float* fc2b = (const float*)d_in[11];
    float* out = (float*)d_out;

    // ---- workspace layout ----
    float* h       = (float*)d_ws;               // 3.2M f
    float* pooledp = h + N_NODES * D1;           // 4*128*64 f
    float* bias4   = pooledp + 4 * N_GRAPHS * D1;
    int* deg       = (int*)(bias4 + 256);        // N_NODES
    u16* srcidx    = (u16*)(deg + N_NODES);      // N_NODES*CAP u16 = 6.4 MB
    size_t soff = ((size_t)(srcidx + N_NODES * CAP) + 15) & ~(size_t)15;
    u16* m16    = (u16*)soff;                    // 3.2M u16
    short* hhi  = (short*)(m16 + N_NODES * D1);  // 3.2M
    short* hlo  = hhi + N_NODES * D1;
    short* aghi = hlo + N_NODES * D1;
    short* aglo = aghi + N_NODES * D1;
    short* Bh   = aglo + N_NODES * D1;           // 32768
    short* Bl   = Bh + 32768;

    hipMemsetAsync(deg, 0, N_NODES * sizeof(int), stream);
    // fused: fill first (latency-bound), then pack + mm L0 backfill
    fused_head_kernel<<<NFB + 129 + GB, 256, 0, stream>>>(
        ei, deg, srcidx, x, W, wih, whh, bih, bhh, Bh, Bl, bias4, m16);

    // layer 0: agg -> gru(+fused mm of layer 1)
    agg_kernel<<<N_NODES / 4, 256, 0, stream>>>(m16, deg, srcidx, aghi, aglo);
    gru_mfma<true, true, false><<<GB, 256, 0, stream>>>(
        aghi, aglo, hhi, hlo, Bh, Bl, bias4, x, h, W + 4096, m16);
    // layer 1: agg -> gru (last: no hhi/hlo, no mm)
    agg_kernel<<<N_NODES / 4, 256, 0, stream>>>(m16, deg, srcidx, aghi, aglo);
    gru_mfma<false, false, true><<<GB, 256, 0, stream>>>(
        aghi, aglo, hhi, hlo, Bh, Bl, bias4, h, h, nullptr, nullptr);

    pool_kernel<<<4 * N_GRAPHS, 256, 0, stream>>>(h, batch, pooledp);
    head_kernel<<<N_GRAPHS, 64, 0, stream>>>(pooledp, batch, fc1w, fc1b, fc2w, fc2b, out);
}